// Round 1
// baseline (4124.384 us; speedup 1.0000x reference)
//
#include <hip/hip_runtime.h>
#include <math.h>

#define BB 32
#define TS 1024
#define DD 2048
#define UU 1024

#define TT 32   // t-tile per block in score kernel
#define DC 128  // d-chunk staged in LDS

// ---------------------------------------------------------------------------
// Kernel A: qpb[b][u] = sum_d query[b][d]*W2[d][u] + b2[u] + b1[u]
// (b1 folded in here so the score kernel adds a single term)
// ---------------------------------------------------------------------------
__global__ __launch_bounds__(256) void qproj_kernel(
    const float* __restrict__ query, const float* __restrict__ W2,
    const float* __restrict__ b1, const float* __restrict__ b2,
    float* __restrict__ qpb) {
  int idx = blockIdx.x * 256 + threadIdx.x;  // 0..32767
  int b = idx >> 10;
  int u = idx & 1023;
  const float* q = query + b * DD;
  float acc = 0.f;
#pragma unroll 8
  for (int d = 0; d < DD; ++d) acc += q[d] * W2[(size_t)d * UU + u];
  qpb[idx] = acc + b1[u] + b2[u];
}

// ---------------------------------------------------------------------------
// Kernel B: score[b][t] = sum_u tanh(kp[b][t][u] + qpb[b][u]) * V[u] + bv
// where kp = values @ W1, fused (keys_proj never materialized).
// Block: 256 threads, one (b, 32-t tile). Each thread owns u = tid + 256k,
// k=0..3, for all 32 t -> 128 fp32 accumulators in VGPRs.
// ---------------------------------------------------------------------------
__global__ __launch_bounds__(256) void score_kernel(
    const float* __restrict__ values, const float* __restrict__ W1,
    const float* __restrict__ qpb, const float* __restrict__ V,
    const float* __restrict__ bv, float* __restrict__ score) {
  __shared__ float lds_v[TT][DC];   // 16 KB
  __shared__ float red[4][TT];

  const int tid = threadIdx.x;
  const int blk = blockIdx.x;       // 0..1023
  const int b = blk >> 5;           // 32 t-tiles per batch
  const int t0 = (blk & 31) * TT;

  float acc[TT][4];
#pragma unroll
  for (int t = 0; t < TT; ++t)
#pragma unroll
    for (int k = 0; k < 4; ++k) acc[t][k] = 0.f;

  const float* vbase = values + ((size_t)b * TS + t0) * DD;

  for (int d0 = 0; d0 < DD; d0 += DC) {
    __syncthreads();  // protect lds_v from previous chunk's readers
    // stage values[t0..t0+31][d0..d0+127] -> LDS, float4, coalesced
#pragma unroll
    for (int i = 0; i < 4; ++i) {
      int idx = tid + 256 * i;          // 0..1023 float4 slots
      int t = idx >> 5;                 // 32 float4 per row
      int dv = idx & 31;
      float4 val = *(const float4*)(vbase + (size_t)t * DD + d0 + dv * 4);
      *(float4*)&lds_v[t][dv * 4] = val;
    }
    __syncthreads();

    for (int d = 0; d < DC; ++d) {
      const float* wrow = W1 + (size_t)(d0 + d) * UU + tid;
      float w0 = wrow[0];
      float w1 = wrow[256];
      float w2 = wrow[512];
      float w3 = wrow[768];
#pragma unroll
      for (int t = 0; t < TT; ++t) {
        float v = lds_v[t][d];          // wave-uniform broadcast, no conflict
        acc[t][0] += v * w0;
        acc[t][1] += v * w1;
        acc[t][2] += v * w2;
        acc[t][3] += v * w3;
      }
    }
  }

  // epilogue: tanh + V-dot, then block reduction over the 256 u-threads
  const float q0 = qpb[b * UU + tid];
  const float q1 = qpb[b * UU + tid + 256];
  const float q2 = qpb[b * UU + tid + 512];
  const float q3 = qpb[b * UU + tid + 768];
  const float v0 = V[tid], v1 = V[tid + 256], v2 = V[tid + 512], v3 = V[tid + 768];
  const int lane = tid & 63, wave = tid >> 6;

#pragma unroll
  for (int t = 0; t < TT; ++t) {
    float p = tanhf(acc[t][0] + q0) * v0 + tanhf(acc[t][1] + q1) * v1 +
              tanhf(acc[t][2] + q2) * v2 + tanhf(acc[t][3] + q3) * v3;
#pragma unroll
    for (int off = 32; off > 0; off >>= 1) p += __shfl_down(p, off, 64);
    if (lane == 0) red[wave][t] = p;
  }
  __syncthreads();
  if (tid < TT) {
    float s = red[0][tid] + red[1][tid] + red[2][tid] + red[3][tid] + bv[0];
    score[b * TS + t0 + tid] = s;
  }
}

// ---------------------------------------------------------------------------
// Kernel C: softmax over T per batch, in-place (score -> weights)
// ---------------------------------------------------------------------------
__global__ __launch_bounds__(256) void softmax_kernel(float* __restrict__ sw) {
  __shared__ float red[256];
  const int b = blockIdx.x;
  const int tid = threadIdx.x;
  float* s = sw + b * TS;

  float vals[4];
  float m = -1e30f;
#pragma unroll
  for (int i = 0; i < 4; ++i) {
    vals[i] = s[tid + 256 * i];
    m = fmaxf(m, vals[i]);
  }
  red[tid] = m;
  __syncthreads();
  for (int off = 128; off > 0; off >>= 1) {
    if (tid < off) red[tid] = fmaxf(red[tid], red[tid + off]);
    __syncthreads();
  }
  m = red[0];
  __syncthreads();

  float sum = 0.f;
#pragma unroll
  for (int i = 0; i < 4; ++i) {
    vals[i] = expf(vals[i] - m);
    sum += vals[i];
  }
  red[tid] = sum;
  __syncthreads();
  for (int off = 128; off > 0; off >>= 1) {
    if (tid < off) red[tid] += red[tid + off];
    __syncthreads();
  }
  const float inv = 1.f / red[0];
#pragma unroll
  for (int i = 0; i < 4; ++i) s[tid + 256 * i] = vals[i] * inv;
}

// ---------------------------------------------------------------------------
// Kernel D: context[b][d] = sum_t weights[b][t] * values[b][t][d]
// Block: 256 threads, one (b, 256-d chunk). Weights preloaded in LDS.
// ---------------------------------------------------------------------------
__global__ __launch_bounds__(256) void context_kernel(
    const float* __restrict__ values, const float* __restrict__ weights,
    float* __restrict__ context) {
  __shared__ float wl[TS];
  const int b = blockIdx.x >> 3;            // 8 d-chunks per batch
  const int d0 = (blockIdx.x & 7) * 256;
  const int tid = threadIdx.x;
#pragma unroll
  for (int i = 0; i < 4; ++i) wl[tid + 256 * i] = weights[b * TS + tid + 256 * i];
  __syncthreads();

  const float* vb = values + (size_t)b * TS * DD + d0 + tid;
  float acc = 0.f;
#pragma unroll 8
  for (int t = 0; t < TS; ++t) acc += wl[t] * vb[(size_t)t * DD];
  context[b * DD + d0 + tid] = acc;
}

// ---------------------------------------------------------------------------
extern "C" void kernel_launch(void* const* d_in, const int* in_sizes, int n_in,
                              void* d_out, int out_size, void* d_ws, size_t ws_size,
                              hipStream_t stream) {
  const float* query  = (const float*)d_in[0];
  const float* values = (const float*)d_in[1];
  const float* W1     = (const float*)d_in[2];
  const float* b1     = (const float*)d_in[3];
  const float* W2     = (const float*)d_in[4];
  const float* b2     = (const float*)d_in[5];
  const float* V      = (const float*)d_in[6];
  const float* bv     = (const float*)d_in[7];

  float* out = (float*)d_out;
  float* context = out;            // B*D = 65536 floats (output 0)
  float* weights = out + BB * DD;  // B*T = 32768 floats (output 1)

  // Scratch plan (no d_ws needed):
  //  - qp lives temporarily in the context region (overwritten by kernel D)
  //  - scores live in the weights region; softmax runs in-place
  float* qpb   = context;  // B*U = 32768 <= 65536, overwritten later
  float* score = weights;

  qproj_kernel<<<128, 256, 0, stream>>>(query, W2, b1, b2, qpb);
  score_kernel<<<BB * (TS / TT), 256, 0, stream>>>(values, W1, qpb, V, bv, score);
  softmax_kernel<<<BB, 256, 0, stream>>>(score);
  context_kernel<<<BB * 8, 256, 0, stream>>>(values, weights, context);
}

// Round 3
// 832.000 us; speedup vs baseline: 4.9572x; 4.9572x over previous
//
#include <hip/hip_runtime.h>
#include <math.h>

#define BB 32
#define TS 1024
#define DD 2048
#define UU 1024

typedef _Float16 f16x8 __attribute__((ext_vector_type(8)));
typedef _Float16 f16x2 __attribute__((ext_vector_type(2)));
typedef __fp16 fp16x2 __attribute__((ext_vector_type(2)));
typedef float f32x4 __attribute__((ext_vector_type(4)));

union H8 { f16x8 v; f16x2 p[4]; };

static __device__ inline f16x2 pk(float a, float b) {
  fp16x2 r = __builtin_amdgcn_cvt_pkrtz(a, b);
  return __builtin_bit_cast(f16x2, r);
}

// ---------------------------------------------------------------------------
// zero the score buffer (atomic accumulation target)
// ---------------------------------------------------------------------------
__global__ void zero_kernel(float* __restrict__ p) {
  p[blockIdx.x * 1024 + threadIdx.x] = 0.f;
}

// ---------------------------------------------------------------------------
// Kernel A: qpb[b][u] = sum_d query[b][d]*W2[d][u] + b2[u] + b1[u]   (fp32)
// ---------------------------------------------------------------------------
__global__ __launch_bounds__(256) void qproj_kernel(
    const float* __restrict__ query, const float* __restrict__ W2,
    const float* __restrict__ b1, const float* __restrict__ b2,
    float* __restrict__ qpb) {
  int idx = blockIdx.x * 256 + threadIdx.x;  // 0..32767
  int b = idx >> 10;
  int u = idx & 1023;
  const float* q = query + b * DD;
  float acc = 0.f;
#pragma unroll 8
  for (int d = 0; d < DD; ++d) acc += q[d] * W2[(size_t)d * UU + u];
  qpb[idx] = acc + b1[u] + b2[u];
}

// ---------------------------------------------------------------------------
// Kernel B: fused score GEMM.
//   kp[m][u] = sum_k values_flat[m][k] * W1[k][u]     (fp16 MFMA, fp32 acc)
//   score[m] += sum_{u in n-block} tanh(kp + qpb[b][u]) * V[u]   (atomic)
// m = b*1024 + t (flat M = 32768). Tile 128(M) x 128(N), BK = 32.
// 4 waves in 2x2; each wave 64x64 via 4x4 frags of 16x16x32.
// LDS layout (fragment-ordered): x[khi(4)][row(128)][klo(8)] fp16.
// ---------------------------------------------------------------------------
__global__ __launch_bounds__(256) void score_gemm_kernel(
    const float* __restrict__ values, const float* __restrict__ W1,
    const float* __restrict__ qpb, const float* __restrict__ V,
    float* __restrict__ score) {
  __shared__ _Float16 aS[4 * 128 * 8];  // 8 KB
  __shared__ _Float16 bS[4 * 128 * 8];  // 8 KB

  const int tid = threadIdx.x;
  const int mBase = (blockIdx.x >> 3) * 128;  // 256 m-blocks
  const int nBase = (blockIdx.x & 7) * 128;   // 8 n-blocks (siblings adjacent)

  // staging addressing (constant across K-loop)
  const int am = tid >> 1;                 // A row this thread stages
  const int akh = (tid & 1) * 16;          // A k-offset (16 wide)
  const float* aG = values + (size_t)(mBase + am) * DD + akh;
  const int aOff0 = (((tid & 1) * 2) * 128 + am) * 8;  // khi chunk 0
  const int bu2 = (tid & 63) * 2;          // B u-pair
  const int bkq = tid >> 6;                // B khi group
  const float* bG = W1 + (size_t)(bkq * 8) * UU + nBase + bu2;
  const int bOff0 = (bkq * 128 + bu2) * 8;

  // wave / fragment addressing
  const int lane = tid & 63;
  const int wave = tid >> 6;
  const int wm = (wave & 1) * 64;
  const int wn = (wave >> 1) * 64;
  const int quad = lane >> 4;
  const int c16 = lane & 15;

  f32x4 acc[4][4];
#pragma unroll
  for (int mi = 0; mi < 4; ++mi)
#pragma unroll
    for (int ni = 0; ni < 4; ++ni) acc[mi][ni] = (f32x4)0.f;

  for (int k0 = 0; k0 < DD; k0 += 32) {
    // global loads for this iteration (fp32)
    float4 a0 = *(const float4*)(aG + k0 + 0);
    float4 a1 = *(const float4*)(aG + k0 + 4);
    float4 a2 = *(const float4*)(aG + k0 + 8);
    float4 a3 = *(const float4*)(aG + k0 + 12);
    const float* bRow = bG + (size_t)k0 * UU;
    float2 g0 = *(const float2*)(bRow + 0 * UU);
    float2 g1 = *(const float2*)(bRow + 1 * UU);
    float2 g2 = *(const float2*)(bRow + 2 * UU);
    float2 g3 = *(const float2*)(bRow + 3 * UU);
    float2 g4 = *(const float2*)(bRow + 4 * UU);
    float2 g5 = *(const float2*)(bRow + 5 * UU);
    float2 g6 = *(const float2*)(bRow + 6 * UU);
    float2 g7 = *(const float2*)(bRow + 7 * UU);

    __syncthreads();  // previous iteration's readers done

    H8 ha0, ha1, hb0, hb1;
    ha0.p[0] = pk(a0.x, a0.y); ha0.p[1] = pk(a0.z, a0.w);
    ha0.p[2] = pk(a1.x, a1.y); ha0.p[3] = pk(a1.z, a1.w);
    ha1.p[0] = pk(a2.x, a2.y); ha1.p[1] = pk(a2.z, a2.w);
    ha1.p[2] = pk(a3.x, a3.y); ha1.p[3] = pk(a3.z, a3.w);
    *(f16x8*)&aS[aOff0] = ha0.v;
    *(f16x8*)&aS[aOff0 + 1024] = ha1.v;  // khi+1 chunk

    hb0.p[0] = pk(g0.x, g1.x); hb0.p[1] = pk(g2.x, g3.x);
    hb0.p[2] = pk(g4.x, g5.x); hb0.p[3] = pk(g6.x, g7.x);
    hb1.p[0] = pk(g0.y, g1.y); hb1.p[1] = pk(g2.y, g3.y);
    hb1.p[2] = pk(g4.y, g5.y); hb1.p[3] = pk(g6.y, g7.y);
    *(f16x8*)&bS[bOff0] = hb0.v;
    *(f16x8*)&bS[bOff0 + 8] = hb1.v;     // u2+1

    __syncthreads();  // tiles ready

    f16x8 af[4], bf[4];
#pragma unroll
    for (int i = 0; i < 4; ++i) {
      af[i] = *(const f16x8*)&aS[(quad * 128 + wm + i * 16 + c16) * 8];
      bf[i] = *(const f16x8*)&bS[(quad * 128 + wn + i * 16 + c16) * 8];
    }
#pragma unroll
    for (int mi = 0; mi < 4; ++mi)
#pragma unroll
      for (int ni = 0; ni < 4; ++ni)
        acc[mi][ni] = __builtin_amdgcn_mfma_f32_16x16x32_f16(
            af[mi], bf[ni], acc[mi][ni], 0, 0, 0);
  }

  // epilogue: tanh(acc + qp) * V, reduce over u (16 cols x 4 ni), atomicAdd
  const int b = mBase >> 10;
  float qv[4], vv[4];
#pragma unroll
  for (int ni = 0; ni < 4; ++ni) {
    int ug = nBase + wn + ni * 16 + c16;
    qv[ni] = qpb[b * UU + ug];
    vv[ni] = V[ug];
  }
#pragma unroll
  for (int mi = 0; mi < 4; ++mi) {
#pragma unroll
    for (int reg = 0; reg < 4; ++reg) {
      float p = tanhf(acc[mi][0][reg] + qv[0]) * vv[0] +
                tanhf(acc[mi][1][reg] + qv[1]) * vv[1] +
                tanhf(acc[mi][2][reg] + qv[2]) * vv[2] +
                tanhf(acc[mi][3][reg] + qv[3]) * vv[3];
      // reduce across the 16 columns (lanes sharing quad)
      p += __shfl_xor(p, 1, 64);
      p += __shfl_xor(p, 2, 64);
      p += __shfl_xor(p, 4, 64);
      p += __shfl_xor(p, 8, 64);
      if (c16 == 0) {
        int mrow = mBase + wm + mi * 16 + quad * 4 + reg;
        atomicAdd(&score[mrow], p);
      }
    }
  }
}

// ---------------------------------------------------------------------------
// Kernel C: softmax over T per batch, in-place (score -> weights)
// ---------------------------------------------------------------------------
__global__ __launch_bounds__(256) void softmax_kernel(float* __restrict__ sw) {
  __shared__ float red[256];
  const int b = blockIdx.x;
  const int tid = threadIdx.x;
  float* s = sw + b * TS;

  float vals[4];
  float m = -1e30f;
#pragma unroll
  for (int i = 0; i < 4; ++i) {
    vals[i] = s[tid + 256 * i];
    m = fmaxf(m, vals[i]);
  }
  red[tid] = m;
  __syncthreads();
  for (int off = 128; off > 0; off >>= 1) {
    if (tid < off) red[tid] = fmaxf(red[tid], red[tid + off]);
    __syncthreads();
  }
  m = red[0];
  __syncthreads();

  float sum = 0.f;
#pragma unroll
  for (int i = 0; i < 4; ++i) {
    vals[i] = expf(vals[i] - m);
    sum += vals[i];
  }
  red[tid] = sum;
  __syncthreads();
  for (int off = 128; off > 0; off >>= 1) {
    if (tid < off) red[tid] += red[tid + off];
    __syncthreads();
  }
  const float inv = 1.f / red[0];
#pragma unroll
  for (int i = 0; i < 4; ++i) s[tid + 256 * i] = vals[i] * inv;
}

// ---------------------------------------------------------------------------
// Kernel D: context[b][d] = sum_t weights[b][t] * values[b][t][d]
// 1024 threads: 4 t-slices x 256 d. LDS partial reduction across slices.
// ---------------------------------------------------------------------------
__global__ __launch_bounds__(1024) void context_kernel(
    const float* __restrict__ values, const float* __restrict__ weights,
    float* __restrict__ context) {
  __shared__ float wl[TS];
  __shared__ float part[3][256];
  const int b = blockIdx.x >> 3;
  const int d0 = (blockIdx.x & 7) * 256;
  const int tid = threadIdx.x;
  const int slice = tid >> 8;
  const int dl = tid & 255;

  wl[tid] = weights[b * TS + tid];
  __syncthreads();

  const float* vb = values + ((size_t)b * TS + slice * 256) * DD + d0 + dl;
  float acc = 0.f;
#pragma unroll 8
  for (int t = 0; t < 256; ++t) acc += wl[slice * 256 + t] * vb[(size_t)t * DD];

  if (slice > 0) part[slice - 1][dl] = acc;
  __syncthreads();
  if (slice == 0)
    context[b * DD + d0 + dl] = acc + part[0][dl] + part[1][dl] + part[2][dl];
}

// ---------------------------------------------------------------------------
extern "C" void kernel_launch(void* const* d_in, const int* in_sizes, int n_in,
                              void* d_out, int out_size, void* d_ws, size_t ws_size,
                              hipStream_t stream) {
  const float* query  = (const float*)d_in[0];
  const float* values = (const float*)d_in[1];
  const float* W1     = (const float*)d_in[2];
  const float* b1     = (const float*)d_in[3];
  const float* W2     = (const float*)d_in[4];
  const float* b2     = (const float*)d_in[5];
  const float* V      = (const float*)d_in[6];
  // d_in[7] = bv: a constant shift on scores cancels in softmax and does not
  // affect context — intentionally unused.

  float* out = (float*)d_out;
  float* context = out;            // B*D = 65536 floats (output 0)
  float* weights = out + BB * DD;  // B*T = 32768 floats (output 1)

  float* qpb   = context;  // B*U = 32768 <= 65536, overwritten by context later
  float* score = weights;  // softmax runs in-place

  zero_kernel<<<TS * BB / 1024, 1024, 0, stream>>>(score);
  qproj_kernel<<<128, 256, 0, stream>>>(query, W2, b1, b2, qpb);
  score_gemm_kernel<<<(BB * TS / 128) * (UU / 128), 256, 0, stream>>>(
      values, W1, qpb, V, score);
  softmax_kernel<<<BB, 256, 0, stream>>>(score);
  context_kernel<<<BB * 8, 1024, 0, stream>>>(values, weights, context);
}

// Round 4
// 788.297 us; speedup vs baseline: 5.2320x; 1.0554x over previous
//
#include <hip/hip_runtime.h>
#include <math.h>

#define BB 32
#define TS 1024
#define DD 2048
#define UU 1024

typedef _Float16 f16x8 __attribute__((ext_vector_type(8)));
typedef _Float16 f16x2 __attribute__((ext_vector_type(2)));
typedef __fp16 fp16x2 __attribute__((ext_vector_type(2)));
typedef float f32x4 __attribute__((ext_vector_type(4)));

union H8 { f16x8 v; f16x2 p[4]; };

static __device__ inline f16x2 pk(float a, float b) {
  fp16x2 r = __builtin_amdgcn_cvt_pkrtz(a, b);
  return __builtin_bit_cast(f16x2, r);
}

// async global->LDS, 16B per lane; LDS dest = wave-uniform base + lane*16
static __device__ inline void gld16(const _Float16* g, _Float16* l) {
  __builtin_amdgcn_global_load_lds(
      (const __attribute__((address_space(1))) void*)g,
      (__attribute__((address_space(3))) void*)l, 16, 0, 0);
}

// ---------------------------------------------------------------------------
__global__ void zero_kernel(float* __restrict__ p) {
  p[blockIdx.x * 1024 + threadIdx.x] = 0.f;
}

// ---------------------------------------------------------------------------
// Kernel A: qpb[b][u] = sum_d query[b][d]*W2[d][u] + b2[u] + b1[u]
// 256 blocks x 512 thr; 4 d-slices of 512, LDS partial reduce.
// ---------------------------------------------------------------------------
__global__ __launch_bounds__(512) void qproj_kernel(
    const float* __restrict__ query, const float* __restrict__ W2,
    const float* __restrict__ b1, const float* __restrict__ b2,
    float* __restrict__ qpb) {
  __shared__ float part[3][128];
  const int b = blockIdx.x >> 3, u0 = (blockIdx.x & 7) * 128;
  const int tid = threadIdx.x, ul = tid & 127, sl = tid >> 7;
  const float* q = query + b * DD + sl * 512;
  const float* w = W2 + (size_t)(sl * 512) * UU + u0 + ul;
  float acc = 0.f;
#pragma unroll 8
  for (int d = 0; d < 512; ++d) acc += q[d] * w[(size_t)d * UU];
  if (sl) part[sl - 1][ul] = acc;
  __syncthreads();
  if (sl == 0) {
    int u = u0 + ul;
    qpb[b * UU + u] = acc + part[0][ul] + part[1][ul] + part[2][ul] + b1[u] + b2[u];
  }
}

// ---------------------------------------------------------------------------
// Pre-pass 1: values fp32 -> fp16 (flat copy into ws)
// ---------------------------------------------------------------------------
__global__ __launch_bounds__(256) void cvt_values_kernel(
    const float* __restrict__ v, _Float16* __restrict__ vh) {
  size_t i = ((size_t)blockIdx.x * 256 + threadIdx.x) * 8;
  float4 x = *(const float4*)(v + i);
  float4 y = *(const float4*)(v + i + 4);
  H8 h;
  h.p[0] = pk(x.x, x.y); h.p[1] = pk(x.z, x.w);
  h.p[2] = pk(y.x, y.y); h.p[3] = pk(y.z, y.w);
  *(f16x8*)(vh + i) = h.v;
}

// ---------------------------------------------------------------------------
// Pre-pass 2: W1 [k=2048][u=1024] fp32 -> W1T [u][k] fp16 (LDS-tiled transpose)
// ---------------------------------------------------------------------------
__global__ __launch_bounds__(256) void w1t_kernel(
    const float* __restrict__ W1, _Float16* __restrict__ w1t) {
  __shared__ float t[32][33];
  const int k0 = (blockIdx.x >> 5) * 32;
  const int u0 = (blockIdx.x & 31) * 32;
  const int tid = threadIdx.x;
  const int r = tid >> 5, c = tid & 31;
#pragma unroll
  for (int i = 0; i < 4; ++i)
    t[r + i * 8][c] = W1[(size_t)(k0 + r + i * 8) * UU + u0 + c];
  __syncthreads();
#pragma unroll
  for (int i = 0; i < 4; ++i)
    w1t[(size_t)(u0 + r + i * 8) * DD + k0 + c] = (_Float16)t[c][r + i * 8];
}

// ---------------------------------------------------------------------------
// Kernel B (ws path): m97-style fused score GEMM, fp16 inputs.
// Tile 128(M) x 128(N), BK=32, 4 waves 2x2, 4x4 frags of 16x16x32.
// LDS layout [khi(4)][row(128)][klo(8)] fp16 = 8 KB per operand, filled by
// global_load_lds: slab s (khi=s>>1, half=s&1) = 64 granules, lane -> row
// half*64+lane. Wave w stages slabs w and w+4 (same rows, khi+2 -> +16 elems).
// ---------------------------------------------------------------------------
__global__ __launch_bounds__(256) void score_gemm_h_kernel(
    const _Float16* __restrict__ vh, const _Float16* __restrict__ w1t,
    const float* __restrict__ qpb, const float* __restrict__ V,
    float* __restrict__ score) {
  __shared__ _Float16 aS[4 * 128 * 8];  // 8 KB
  __shared__ _Float16 bS[4 * 128 * 8];  // 8 KB

  const int tid = threadIdx.x;
  const int mBase = (blockIdx.x >> 3) * 128;
  const int nBase = (blockIdx.x & 7) * 128;

  const int lane = tid & 63;
  const int wave = tid >> 6;
  const int wm = (wave & 1) * 64;
  const int wn = (wave >> 1) * 64;
  const int quad = lane >> 4;
  const int c16 = lane & 15;

  // staging bases (k0 added in loop). Slab s=wave: row=(wave&1)*64+lane,
  // khi=wave>>1; slab s2=wave+4: same row, khi+2 (= +16 fp16 elems).
  const _Float16* gA = vh + (size_t)(mBase + (wave & 1) * 64 + lane) * DD + (wave >> 1) * 8;
  const _Float16* gB = w1t + (size_t)(nBase + (wave & 1) * 64 + lane) * DD + (wave >> 1) * 8;
  _Float16* lA1 = &aS[wave * 512];
  _Float16* lA2 = &aS[wave * 512 + 2048];
  _Float16* lB1 = &bS[wave * 512];
  _Float16* lB2 = &bS[wave * 512 + 2048];

  f32x4 acc[4][4];
#pragma unroll
  for (int mi = 0; mi < 4; ++mi)
#pragma unroll
    for (int ni = 0; ni < 4; ++ni) acc[mi][ni] = (f32x4)0.f;

  for (int k0 = 0; k0 < DD; k0 += 32) {
    __syncthreads();  // previous iteration's readers done
    gld16(gA + k0, lA1);
    gld16(gA + k0 + 16, lA2);
    gld16(gB + k0, lB1);
    gld16(gB + k0 + 16, lB2);
    __syncthreads();  // barrier drains vmcnt -> tiles ready

    f16x8 af[4], bf[4];
#pragma unroll
    for (int i = 0; i < 4; ++i) {
      af[i] = *(const f16x8*)&aS[(quad * 128 + wm + i * 16 + c16) * 8];
      bf[i] = *(const f16x8*)&bS[(quad * 128 + wn + i * 16 + c16) * 8];
    }
#pragma unroll
    for (int mi = 0; mi < 4; ++mi)
#pragma unroll
      for (int ni = 0; ni < 4; ++ni)
        acc[mi][ni] = __builtin_amdgcn_mfma_f32_16x16x32_f16(
            af[mi], bf[ni], acc[mi][ni], 0, 0, 0);
  }

  // epilogue: tanh(acc + qp) * V, reduce over 16 cols x 4 ni, atomicAdd
  const int b = mBase >> 10;
  float qv[4], vv[4];
#pragma unroll
  for (int ni = 0; ni < 4; ++ni) {
    int ug = nBase + wn + ni * 16 + c16;
    qv[ni] = qpb[b * UU + ug];
    vv[ni] = V[ug];
  }
#pragma unroll
  for (int mi = 0; mi < 4; ++mi) {
#pragma unroll
    for (int reg = 0; reg < 4; ++reg) {
      float p = tanhf(acc[mi][0][reg] + qv[0]) * vv[0] +
                tanhf(acc[mi][1][reg] + qv[1]) * vv[1] +
                tanhf(acc[mi][2][reg] + qv[2]) * vv[2] +
                tanhf(acc[mi][3][reg] + qv[3]) * vv[3];
      p += __shfl_xor(p, 1, 64);
      p += __shfl_xor(p, 2, 64);
      p += __shfl_xor(p, 4, 64);
      p += __shfl_xor(p, 8, 64);
      if (c16 == 0) {
        int mrow = mBase + wm + mi * 16 + quad * 4 + reg;
        atomicAdd(&score[mrow], p);
      }
    }
  }
}

// ---------------------------------------------------------------------------
// Kernel B fallback (small ws): round-3 fused GEMM, fp32 in, cvt per tile.
// ---------------------------------------------------------------------------
__global__ __launch_bounds__(256) void score_gemm_kernel(
    const float* __restrict__ values, const float* __restrict__ W1,
    const float* __restrict__ qpb, const float* __restrict__ V,
    float* __restrict__ score) {
  __shared__ _Float16 aS[4 * 128 * 8];
  __shared__ _Float16 bS[4 * 128 * 8];

  const int tid = threadIdx.x;
  const int mBase = (blockIdx.x >> 3) * 128;
  const int nBase = (blockIdx.x & 7) * 128;

  const int am = tid >> 1;
  const int akh = (tid & 1) * 16;
  const float* aG = values + (size_t)(mBase + am) * DD + akh;
  const int aOff0 = (((tid & 1) * 2) * 128 + am) * 8;
  const int bu2 = (tid & 63) * 2;
  const int bkq = tid >> 6;
  const float* bG = W1 + (size_t)(bkq * 8) * UU + nBase + bu2;
  const int bOff0 = (bkq * 128 + bu2) * 8;

  const int lane = tid & 63;
  const int wave = tid >> 6;
  const int wm = (wave & 1) * 64;
  const int wn = (wave >> 1) * 64;
  const int quad = lane >> 4;
  const int c16 = lane & 15;

  f32x4 acc[4][4];
#pragma unroll
  for (int mi = 0; mi < 4; ++mi)
#pragma unroll
    for (int ni = 0; ni < 4; ++ni) acc[mi][ni] = (f32x4)0.f;

  for (int k0 = 0; k0 < DD; k0 += 32) {
    float4 a0 = *(const float4*)(aG + k0 + 0);
    float4 a1 = *(const float4*)(aG + k0 + 4);
    float4 a2 = *(const float4*)(aG + k0 + 8);
    float4 a3 = *(const float4*)(aG + k0 + 12);
    const float* bRow = bG + (size_t)k0 * UU;
    float2 g0 = *(const float2*)(bRow + 0 * UU);
    float2 g1 = *(const float2*)(bRow + 1 * UU);
    float2 g2 = *(const float2*)(bRow + 2 * UU);
    float2 g3 = *(const float2*)(bRow + 3 * UU);
    float2 g4 = *(const float2*)(bRow + 4 * UU);
    float2 g5 = *(const float2*)(bRow + 5 * UU);
    float2 g6 = *(const float2*)(bRow + 6 * UU);
    float2 g7 = *(const float2*)(bRow + 7 * UU);

    __syncthreads();

    H8 ha0, ha1, hb0, hb1;
    ha0.p[0] = pk(a0.x, a0.y); ha0.p[1] = pk(a0.z, a0.w);
    ha0.p[2] = pk(a1.x, a1.y); ha0.p[3] = pk(a1.z, a1.w);
    ha1.p[0] = pk(a2.x, a2.y); ha1.p[1] = pk(a2.z, a2.w);
    ha1.p[2] = pk(a3.x, a3.y); ha1.p[3] = pk(a3.z, a3.w);
    *(f16x8*)&aS[aOff0] = ha0.v;
    *(f16x8*)&aS[aOff0 + 1024] = ha1.v;

    hb0.p[0] = pk(g0.x, g1.x); hb0.p[1] = pk(g2.x, g3.x);
    hb0.p[2] = pk(g4.x, g5.x); hb0.p[3] = pk(g6.x, g7.x);
    hb1.p[0] = pk(g0.y, g1.y); hb1.p[1] = pk(g2.y, g3.y);
    hb1.p[2] = pk(g4.y, g5.y); hb1.p[3] = pk(g6.y, g7.y);
    *(f16x8*)&bS[bOff0] = hb0.v;
    *(f16x8*)&bS[bOff0 + 8] = hb1.v;

    __syncthreads();

    f16x8 af[4], bf[4];
#pragma unroll
    for (int i = 0; i < 4; ++i) {
      af[i] = *(const f16x8*)&aS[(quad * 128 + wm + i * 16 + c16) * 8];
      bf[i] = *(const f16x8*)&bS[(quad * 128 + wn + i * 16 + c16) * 8];
    }
#pragma unroll
    for (int mi = 0; mi < 4; ++mi)
#pragma unroll
      for (int ni = 0; ni < 4; ++ni)
        acc[mi][ni] = __builtin_amdgcn_mfma_f32_16x16x32_f16(
            af[mi], bf[ni], acc[mi][ni], 0, 0, 0);
  }

  const int b = mBase >> 10;
  float qv[4], vv[4];
#pragma unroll
  for (int ni = 0; ni < 4; ++ni) {
    int ug = nBase + wn + ni * 16 + c16;
    qv[ni] = qpb[b * UU + ug];
    vv[ni] = V[ug];
  }
#pragma unroll
  for (int mi = 0; mi < 4; ++mi) {
#pragma unroll
    for (int reg = 0; reg < 4; ++reg) {
      float p = tanhf(acc[mi][0][reg] + qv[0]) * vv[0] +
                tanhf(acc[mi][1][reg] + qv[1]) * vv[1] +
                tanhf(acc[mi][2][reg] + qv[2]) * vv[2] +
                tanhf(acc[mi][3][reg] + qv[3]) * vv[3];
      p += __shfl_xor(p, 1, 64);
      p += __shfl_xor(p, 2, 64);
      p += __shfl_xor(p, 4, 64);
      p += __shfl_xor(p, 8, 64);
      if (c16 == 0) {
        int mrow = mBase + wm + mi * 16 + quad * 4 + reg;
        atomicAdd(&score[mrow], p);
      }
    }
  }
}

// ---------------------------------------------------------------------------
// Kernel C: softmax over T per batch, in-place
// ---------------------------------------------------------------------------
__global__ __launch_bounds__(256) void softmax_kernel(float* __restrict__ sw) {
  __shared__ float red[256];
  const int b = blockIdx.x;
  const int tid = threadIdx.x;
  float* s = sw + b * TS;

  float vals[4];
  float m = -1e30f;
#pragma unroll
  for (int i = 0; i < 4; ++i) {
    vals[i] = s[tid + 256 * i];
    m = fmaxf(m, vals[i]);
  }
  red[tid] = m;
  __syncthreads();
  for (int off = 128; off > 0; off >>= 1) {
    if (tid < off) red[tid] = fmaxf(red[tid], red[tid + off]);
    __syncthreads();
  }
  m = red[0];
  __syncthreads();

  float sum = 0.f;
#pragma unroll
  for (int i = 0; i < 4; ++i) {
    vals[i] = expf(vals[i] - m);
    sum += vals[i];
  }
  red[tid] = sum;
  __syncthreads();
  for (int off = 128; off > 0; off >>= 1) {
    if (tid < off) red[tid] += red[tid + off];
    __syncthreads();
  }
  const float inv = 1.f / red[0];
#pragma unroll
  for (int i = 0; i < 4; ++i) s[tid + 256 * i] = vals[i] * inv;
}

// ---------------------------------------------------------------------------
// Kernel D: context[b][d] = sum_t weights[b][t] * values[b][t][d]
// ---------------------------------------------------------------------------
__global__ __launch_bounds__(1024) void context_kernel(
    const float* __restrict__ values, const float* __restrict__ weights,
    float* __restrict__ context) {
  __shared__ float wl[TS];
  __shared__ float part[3][256];
  const int b = blockIdx.x >> 3;
  const int d0 = (blockIdx.x & 7) * 256;
  const int tid = threadIdx.x;
  const int slice = tid >> 8;
  const int dl = tid & 255;

  wl[tid] = weights[b * TS + tid];
  __syncthreads();

  const float* vb = values + ((size_t)b * TS + slice * 256) * DD + d0 + dl;
  float acc = 0.f;
#pragma unroll 8
  for (int t = 0; t < 256; ++t) acc += wl[slice * 256 + t] * vb[(size_t)t * DD];

  if (slice > 0) part[slice - 1][dl] = acc;
  __syncthreads();
  if (slice == 0)
    context[b * DD + d0 + dl] = acc + part[0][dl] + part[1][dl] + part[2][dl];
}

// ---------------------------------------------------------------------------
extern "C" void kernel_launch(void* const* d_in, const int* in_sizes, int n_in,
                              void* d_out, int out_size, void* d_ws, size_t ws_size,
                              hipStream_t stream) {
  const float* query  = (const float*)d_in[0];
  const float* values = (const float*)d_in[1];
  const float* W1     = (const float*)d_in[2];
  const float* b1     = (const float*)d_in[3];
  const float* W2     = (const float*)d_in[4];
  const float* b2     = (const float*)d_in[5];
  const float* V      = (const float*)d_in[6];
  // d_in[7] = bv cancels in softmax; unused.

  float* out = (float*)d_out;
  float* context = out;            // B*D (output 0)
  float* weights = out + BB * DD;  // B*T (output 1)

  float* qpb   = context;  // overwritten by context kernel later
  float* score = weights;  // softmax in-place

  // ws plan: vh = values fp16 (134217728 B) + w1t fp16 (4194304 B)
  const size_t need = (size_t)BB * TS * DD * 2 + (size_t)DD * UU * 2;
  const bool big_ws = ws_size >= need;

  zero_kernel<<<TS * BB / 1024, 1024, 0, stream>>>(score);
  qproj_kernel<<<BB * 8, 512, 0, stream>>>(query, W2, b1, b2, qpb);

  if (big_ws) {
    _Float16* vh  = (_Float16*)d_ws;
    _Float16* w1t = vh + (size_t)BB * TS * DD;
    cvt_values_kernel<<<(BB * TS * DD) / (8 * 256), 256, 0, stream>>>(values, vh);
    w1t_kernel<<<(DD / 32) * (UU / 32), 256, 0, stream>>>(W1, w1t);
    score_gemm_h_kernel<<<(BB * TS / 128) * (UU / 128), 256, 0, stream>>>(
        vh, w1t, qpb, V, score);
  } else {
    score_gemm_kernel<<<(BB * TS / 128) * (UU / 128), 256, 0, stream>>>(
        values, W1, qpb, V, score);
  }

  softmax_kernel<<<BB, 256, 0, stream>>>(score);
  context_kernel<<<BB * 8, 1024, 0, stream>>>(values, weights, context);
}

// Round 5
// 665.182 us; speedup vs baseline: 6.2004x; 1.1851x over previous
//
#include <hip/hip_runtime.h>
#include <math.h>

#define BB 32
#define TS 1024
#define DD 2048
#define UU 1024

typedef _Float16 f16x8 __attribute__((ext_vector_type(8)));
typedef _Float16 f16x2 __attribute__((ext_vector_type(2)));
typedef __fp16 fp16x2 __attribute__((ext_vector_type(2)));
typedef float f32x4 __attribute__((ext_vector_type(4)));

union H8 { f16x8 v; f16x2 p[4]; };

static __device__ inline f16x2 pk(float a, float b) {
  fp16x2 r = __builtin_amdgcn_cvt_pkrtz(a, b);
  return __builtin_bit_cast(f16x2, r);
}

// async global->LDS, 16B/lane; global addr is per-lane (pass base+lane*8 elems),
// LDS dest must be wave-uniform (HW adds lane*16).
static __device__ inline void gld16(const _Float16* g, _Float16* l) {
  __builtin_amdgcn_global_load_lds(
      (const __attribute__((address_space(1))) void*)g,
      (__attribute__((address_space(3))) void*)l, 16, 0, 0);
}

// ---------------------------------------------------------------------------
__global__ void zero_kernel(float* __restrict__ p) {
  p[blockIdx.x * 1024 + threadIdx.x] = 0.f;
}

// ---------------------------------------------------------------------------
// Kernel A: qpb[b][u] = sum_d query[b][d]*W2[d][u] + b2[u] + b1[u]
// ---------------------------------------------------------------------------
__global__ __launch_bounds__(512) void qproj_kernel(
    const float* __restrict__ query, const float* __restrict__ W2,
    const float* __restrict__ b1, const float* __restrict__ b2,
    float* __restrict__ qpb) {
  __shared__ float part[3][128];
  const int b = blockIdx.x >> 3, u0 = (blockIdx.x & 7) * 128;
  const int tid = threadIdx.x, ul = tid & 127, sl = tid >> 7;
  const float* q = query + b * DD + sl * 512;
  const float* w = W2 + (size_t)(sl * 512) * UU + u0 + ul;
  float acc = 0.f;
#pragma unroll 8
  for (int d = 0; d < 512; ++d) acc += q[d] * w[(size_t)d * UU];
  if (sl) part[sl - 1][ul] = acc;
  __syncthreads();
  if (sl == 0) {
    int u = u0 + ul;
    qpb[b * UU + u] = acc + part[0][ul] + part[1][ul] + part[2][ul] + b1[u] + b2[u];
  }
}

// ---------------------------------------------------------------------------
// Pre-pass 1: values fp32 -> packed fp16 MFMA image.
// vhp chunk c = mTile*32 + kc holds the 16-KB LDS image of a 128(row)x64(k)
// tile: element order [khi(8)][row(128)][klo(8)].
// LDS round-trip: reads coalesced along k, writes coalesced along image;
// XOR swizzle (row ^ khi) keeps both LDS phases conflict-free.
// ---------------------------------------------------------------------------
__global__ __launch_bounds__(256) void pack_values_kernel(
    const float* __restrict__ v, _Float16* __restrict__ vhp) {
  __shared__ _Float16 img[8192];  // 16 KB
  const int mTile = blockIdx.x >> 5;  // 256
  const int kc = blockIdx.x & 31;     // 32
  const int tid = threadIdx.x;

  // read phase: idx -> (row = idx>>3, khi = idx&7), 32B contiguous per thread
#pragma unroll
  for (int i = 0; i < 4; ++i) {
    int idx = i * 256 + tid;
    int row = idx >> 3, khi = idx & 7;
    const float* src = v + ((size_t)(mTile * 128 + row)) * DD + kc * 64 + khi * 8;
    float4 x = *(const float4*)src;
    float4 y = *(const float4*)(src + 4);
    H8 h;
    h.p[0] = pk(x.x, x.y); h.p[1] = pk(x.z, x.w);
    h.p[2] = pk(y.x, y.y); h.p[3] = pk(y.z, y.w);
    *(f16x8*)&img[(khi * 128 + (row ^ khi)) * 8] = h.v;
  }
  __syncthreads();

  // write phase: linear image order, contiguous 16-B stores
  _Float16* out = vhp + ((size_t)mTile * 32 + kc) * 8192;
#pragma unroll
  for (int i = 0; i < 4; ++i) {
    int p = i * 256 + tid;
    int khi = p >> 7, row = p & 127;
    *(f16x8*)(out + (size_t)p * 8) = *(const f16x8*)&img[(khi * 128 + (row ^ khi)) * 8];
  }
}

// ---------------------------------------------------------------------------
// Pre-pass 2: W1 [k=2048][u=1024] fp32 -> packed fp16 image of W1^T.
// w1p chunk c = nTile*32 + kc: image rows are u_local (128), k-slab 64.
// ---------------------------------------------------------------------------
__global__ __launch_bounds__(256) void pack_w1_kernel(
    const float* __restrict__ W1, _Float16* __restrict__ w1p) {
  __shared__ _Float16 img[8192];
  const int nTile = blockIdx.x >> 5;  // 8
  const int kc = blockIdx.x & 31;     // 32
  const int tid = threadIdx.x;

  // read along u (coalesced), scalar fp16 store with xor swizzle
#pragma unroll
  for (int i = 0; i < 32; ++i) {
    int idx = i * 256 + tid;
    int ul = idx & 127, kl = idx >> 7;
    float x = W1[(size_t)(kc * 64 + kl) * UU + nTile * 128 + ul];
    int khi = kl >> 3, klo = kl & 7;
    img[(khi * 128 + (ul ^ khi)) * 8 + klo] = (_Float16)x;
  }
  __syncthreads();

  _Float16* out = w1p + ((size_t)nTile * 32 + kc) * 8192;
#pragma unroll
  for (int i = 0; i < 4; ++i) {
    int p = i * 256 + tid;
    int khi = p >> 7, row = p & 127;
    *(f16x8*)(out + (size_t)p * 8) = *(const f16x8*)&img[(khi * 128 + (row ^ khi)) * 8];
  }
}

// ---------------------------------------------------------------------------
// Kernel B: fused score GEMM from packed images. Tile 128x128, BK=64.
// XCD swizzle: the 8 n-siblings of an m-tile share one XCD's L2 for A.
// Staging: flat 16-KB chunk copies via global_load_lds (fully coalesced).
// ---------------------------------------------------------------------------
__global__ __launch_bounds__(256) void score_gemm_p_kernel(
    const _Float16* __restrict__ vhp, const _Float16* __restrict__ w1p,
    const float* __restrict__ qpb, const float* __restrict__ V,
    float* __restrict__ score) {
  __shared__ _Float16 aS[8192];  // 16 KB: [khi(8)][row(128)][klo(8)]
  __shared__ _Float16 bS[8192];  // 16 KB

  const int tid = threadIdx.x;
  // swizzle: XCD = blockIdx%8 (heuristic). Same-m siblings -> same XCD.
  const int r = blockIdx.x & 7, q = blockIdx.x >> 3;
  const int mTile = r * 32 + (q >> 3);   // [0,256)
  const int nTile = q & 7;               // [0,8)
  const int mBase = mTile * 128, nBase = nTile * 128;

  const int lane = tid & 63, wave = tid >> 6;
  const int wm = (wave & 1) * 64, wn = (wave >> 1) * 64;
  const int quad = lane >> 4, c16 = lane & 15;

  const _Float16* gA = vhp + (size_t)mTile * 32 * 8192 + lane * 8;
  const _Float16* gB = w1p + (size_t)nTile * 32 * 8192 + lane * 8;

  f32x4 acc[4][4];
#pragma unroll
  for (int mi = 0; mi < 4; ++mi)
#pragma unroll
    for (int ni = 0; ni < 4; ++ni) acc[mi][ni] = (f32x4)0.f;

  for (int kc = 0; kc < 32; ++kc) {
    __syncthreads();  // previous iteration's readers done
#pragma unroll
    for (int j = 0; j < 4; ++j) {
      int s = wave * 4 + j;  // 16 slabs x 1 KB per operand
      gld16(gA + (size_t)kc * 8192 + s * 512, &aS[s * 512]);
      gld16(gB + (size_t)kc * 8192 + s * 512, &bS[s * 512]);
    }
    __syncthreads();  // barrier drains vmcnt -> tiles ready

#pragma unroll
    for (int h = 0; h < 2; ++h) {
      f16x8 af[4], bf[4];
#pragma unroll
      for (int i = 0; i < 4; ++i) {
        af[i] = *(const f16x8*)&aS[((h * 4 + quad) * 128 + wm + i * 16 + c16) * 8];
        bf[i] = *(const f16x8*)&bS[((h * 4 + quad) * 128 + wn + i * 16 + c16) * 8];
      }
#pragma unroll
      for (int mi = 0; mi < 4; ++mi)
#pragma unroll
        for (int ni = 0; ni < 4; ++ni)
          acc[mi][ni] = __builtin_amdgcn_mfma_f32_16x16x32_f16(
              af[mi], bf[ni], acc[mi][ni], 0, 0, 0);
    }
  }

  // epilogue: tanh(acc + qp) * V, reduce over 16 cols x 4 ni, atomicAdd
  const int b = mBase >> 10;
  float qv[4], vv[4];
#pragma unroll
  for (int ni = 0; ni < 4; ++ni) {
    int ug = nBase + wn + ni * 16 + c16;
    qv[ni] = qpb[b * UU + ug];
    vv[ni] = V[ug];
  }
#pragma unroll
  for (int mi = 0; mi < 4; ++mi) {
#pragma unroll
    for (int reg = 0; reg < 4; ++reg) {
      float p = tanhf(acc[mi][0][reg] + qv[0]) * vv[0] +
                tanhf(acc[mi][1][reg] + qv[1]) * vv[1] +
                tanhf(acc[mi][2][reg] + qv[2]) * vv[2] +
                tanhf(acc[mi][3][reg] + qv[3]) * vv[3];
      p += __shfl_xor(p, 1, 64);
      p += __shfl_xor(p, 2, 64);
      p += __shfl_xor(p, 4, 64);
      p += __shfl_xor(p, 8, 64);
      if (c16 == 0) {
        int mrow = mBase + wm + mi * 16 + quad * 4 + reg;
        atomicAdd(&score[mrow], p);
      }
    }
  }
}

// ---------------------------------------------------------------------------
// Kernel B fallback (small ws): round-3 fused GEMM, fp32 in, cvt per tile.
// ---------------------------------------------------------------------------
__global__ __launch_bounds__(256) void score_gemm_kernel(
    const float* __restrict__ values, const float* __restrict__ W1,
    const float* __restrict__ qpb, const float* __restrict__ V,
    float* __restrict__ score) {
  __shared__ _Float16 aS[4 * 128 * 8];
  __shared__ _Float16 bS[4 * 128 * 8];

  const int tid = threadIdx.x;
  const int mBase = (blockIdx.x >> 3) * 128;
  const int nBase = (blockIdx.x & 7) * 128;

  const int am = tid >> 1;
  const int akh = (tid & 1) * 16;
  const float* aG = values + (size_t)(mBase + am) * DD + akh;
  const int aOff0 = (((tid & 1) * 2) * 128 + am) * 8;
  const int bu2 = (tid & 63) * 2;
  const int bkq = tid >> 6;
  const float* bG = W1 + (size_t)(bkq * 8) * UU + nBase + bu2;
  const int bOff0 = (bkq * 128 + bu2) * 8;

  const int lane = tid & 63;
  const int wave = tid >> 6;
  const int wm = (wave & 1) * 64;
  const int wn = (wave >> 1) * 64;
  const int quad = lane >> 4;
  const int c16 = lane & 15;

  f32x4 acc[4][4];
#pragma unroll
  for (int mi = 0; mi < 4; ++mi)
#pragma unroll
    for (int ni = 0; ni < 4; ++ni) acc[mi][ni] = (f32x4)0.f;

  for (int k0 = 0; k0 < DD; k0 += 32) {
    float4 a0 = *(const float4*)(aG + k0 + 0);
    float4 a1 = *(const float4*)(aG + k0 + 4);
    float4 a2 = *(const float4*)(aG + k0 + 8);
    float4 a3 = *(const float4*)(aG + k0 + 12);
    const float* bRow = bG + (size_t)k0 * UU;
    float2 g0 = *(const float2*)(bRow + 0 * UU);
    float2 g1 = *(const float2*)(bRow + 1 * UU);
    float2 g2 = *(const float2*)(bRow + 2 * UU);
    float2 g3 = *(const float2*)(bRow + 3 * UU);
    float2 g4 = *(const float2*)(bRow + 4 * UU);
    float2 g5 = *(const float2*)(bRow + 5 * UU);
    float2 g6 = *(const float2*)(bRow + 6 * UU);
    float2 g7 = *(const float2*)(bRow + 7 * UU);

    __syncthreads();

    H8 ha0, ha1, hb0, hb1;
    ha0.p[0] = pk(a0.x, a0.y); ha0.p[1] = pk(a0.z, a0.w);
    ha0.p[2] = pk(a1.x, a1.y); ha0.p[3] = pk(a1.z, a1.w);
    ha1.p[0] = pk(a2.x, a2.y); ha1.p[1] = pk(a2.z, a2.w);
    ha1.p[2] = pk(a3.x, a3.y); ha1.p[3] = pk(a3.z, a3.w);
    *(f16x8*)&aS[aOff0] = ha0.v;
    *(f16x8*)&aS[aOff0 + 1024] = ha1.v;

    hb0.p[0] = pk(g0.x, g1.x); hb0.p[1] = pk(g2.x, g3.x);
    hb0.p[2] = pk(g4.x, g5.x); hb0.p[3] = pk(g6.x, g7.x);
    hb1.p[0] = pk(g0.y, g1.y); hb1.p[1] = pk(g2.y, g3.y);
    hb1.p[2] = pk(g4.y, g5.y); hb1.p[3] = pk(g6.y, g7.y);
    *(f16x8*)&bS[bOff0] = hb0.v;
    *(f16x8*)&bS[bOff0 + 8] = hb1.v;

    __syncthreads();

    f16x8 af[4], bf[4];
#pragma unroll
    for (int i = 0; i < 4; ++i) {
      af[i] = *(const f16x8*)&aS[(quad * 128 + wm + i * 16 + c16) * 8];
      bf[i] = *(const f16x8*)&bS[(quad * 128 + wn + i * 16 + c16) * 8];
    }
#pragma unroll
    for (int mi = 0; mi < 4; ++mi)
#pragma unroll
      for (int ni = 0; ni < 4; ++ni)
        acc[mi][ni] = __builtin_amdgcn_mfma_f32_16x16x32_f16(
            af[mi], bf[ni], acc[mi][ni], 0, 0, 0);
  }

  const int b = mBase >> 10;
  float qv[4], vv[4];
#pragma unroll
  for (int ni = 0; ni < 4; ++ni) {
    int ug = nBase + wn + ni * 16 + c16;
    qv[ni] = qpb[b * UU + ug];
    vv[ni] = V[ug];
  }
#pragma unroll
  for (int mi = 0; mi < 4; ++mi) {
#pragma unroll
    for (int reg = 0; reg < 4; ++reg) {
      float p = tanhf(acc[mi][0][reg] + qv[0]) * vv[0] +
                tanhf(acc[mi][1][reg] + qv[1]) * vv[1] +
                tanhf(acc[mi][2][reg] + qv[2]) * vv[2] +
                tanhf(acc[mi][3][reg] + qv[3]) * vv[3];
      p += __shfl_xor(p, 1, 64);
      p += __shfl_xor(p, 2, 64);
      p += __shfl_xor(p, 4, 64);
      p += __shfl_xor(p, 8, 64);
      if (c16 == 0) {
        int mrow = mBase + wm + mi * 16 + quad * 4 + reg;
        atomicAdd(&score[mrow], p);
      }
    }
  }
}

// ---------------------------------------------------------------------------
// Kernel C: softmax over T per batch, in-place
// ---------------------------------------------------------------------------
__global__ __launch_bounds__(256) void softmax_kernel(float* __restrict__ sw) {
  __shared__ float red[256];
  const int b = blockIdx.x;
  const int tid = threadIdx.x;
  float* s = sw + b * TS;

  float vals[4];
  float m = -1e30f;
#pragma unroll
  for (int i = 0; i < 4; ++i) {
    vals[i] = s[tid + 256 * i];
    m = fmaxf(m, vals[i]);
  }
  red[tid] = m;
  __syncthreads();
  for (int off = 128; off > 0; off >>= 1) {
    if (tid < off) red[tid] = fmaxf(red[tid], red[tid + off]);
    __syncthreads();
  }
  m = red[0];
  __syncthreads();

  float sum = 0.f;
#pragma unroll
  for (int i = 0; i < 4; ++i) {
    vals[i] = expf(vals[i] - m);
    sum += vals[i];
  }
  red[tid] = sum;
  __syncthreads();
  for (int off = 128; off > 0; off >>= 1) {
    if (tid < off) red[tid] += red[tid + off];
    __syncthreads();
  }
  const float inv = 1.f / red[0];
#pragma unroll
  for (int i = 0; i < 4; ++i) s[tid + 256 * i] = vals[i] * inv;
}

// ---------------------------------------------------------------------------
// Kernel D: context[b][d] = sum_t weights[b][t] * values[b][t][d]
// 512 blocks (b, 128-d chunk) x 1024 thr: 8 t-slices, LDS partial reduce.
// ---------------------------------------------------------------------------
__global__ __launch_bounds__(1024) void context_kernel(
    const float* __restrict__ values, const float* __restrict__ weights,
    float* __restrict__ context) {
  __shared__ float wl[TS];
  __shared__ float part[7][128];
  const int b = blockIdx.x >> 4;
  const int d0 = (blockIdx.x & 15) * 128;
  const int tid = threadIdx.x;
  const int slice = tid >> 7;
  const int dl = tid & 127;

  wl[tid] = weights[b * TS + tid];
  __syncthreads();

  const float* vb = values + ((size_t)b * TS + slice * 128) * DD + d0 + dl;
  float acc = 0.f;
#pragma unroll 8
  for (int t = 0; t < 128; ++t) acc += wl[slice * 128 + t] * vb[(size_t)t * DD];

  if (slice) part[slice - 1][dl] = acc;
  __syncthreads();
  if (slice == 0) {
    float s = acc;
#pragma unroll
    for (int i = 0; i < 7; ++i) s += part[i][dl];
    context[b * DD + d0 + dl] = s;
  }
}

// ---------------------------------------------------------------------------
extern "C" void kernel_launch(void* const* d_in, const int* in_sizes, int n_in,
                              void* d_out, int out_size, void* d_ws, size_t ws_size,
                              hipStream_t stream) {
  const float* query  = (const float*)d_in[0];
  const float* values = (const float*)d_in[1];
  const float* W1     = (const float*)d_in[2];
  const float* b1     = (const float*)d_in[3];
  const float* W2     = (const float*)d_in[4];
  const float* b2     = (const float*)d_in[5];
  const float* V      = (const float*)d_in[6];
  // d_in[7] = bv cancels in softmax; unused.

  float* out = (float*)d_out;
  float* context = out;            // B*D (output 0)
  float* weights = out + BB * DD;  // B*T (output 1)

  float* qpb   = context;  // overwritten by context kernel later
  float* score = weights;  // softmax in-place

  // ws plan: vhp packed fp16 values (134217728 B) + w1p packed fp16 W1T (4 MB)
  const size_t need = (size_t)BB * TS * DD * 2 + (size_t)DD * UU * 2;
  const bool big_ws = ws_size >= need;

  zero_kernel<<<TS * BB / 1024, 1024, 0, stream>>>(score);
  qproj_kernel<<<BB * 8, 512, 0, stream>>>(query, W2, b1, b2, qpb);

  if (big_ws) {
    _Float16* vhp = (_Float16*)d_ws;
    _Float16* w1p = vhp + (size_t)BB * TS * DD;
    pack_values_kernel<<<256 * 32, 256, 0, stream>>>(values, vhp);
    pack_w1_kernel<<<8 * 32, 256, 0, stream>>>(W1, w1p);
    score_gemm_p_kernel<<<(BB * TS / 128) * (UU / 128), 256, 0, stream>>>(
        vhp, w1p, qpb, V, score);
  } else {
    score_gemm_kernel<<<(BB * TS / 128) * (UU / 128), 256, 0, stream>>>(
        values, W1, qpb, V, score);
  }

  softmax_kernel<<<BB, 256, 0, stream>>>(score);
  context_kernel<<<BB * 16, 1024, 0, stream>>>(values, weights, context);
}

// Round 6
// 649.652 us; speedup vs baseline: 6.3486x; 1.0239x over previous
//
#include <hip/hip_runtime.h>
#include <math.h>

#define BB 32
#define TS 1024
#define DD 2048
#define UU 1024

typedef _Float16 f16x8 __attribute__((ext_vector_type(8)));
typedef _Float16 f16x2 __attribute__((ext_vector_type(2)));
typedef __fp16 fp16x2 __attribute__((ext_vector_type(2)));
typedef float f32x4 __attribute__((ext_vector_type(4)));

union H8 { f16x8 v; f16x2 p[4]; };

static __device__ inline f16x2 pk(float a, float b) {
  fp16x2 r = __builtin_amdgcn_cvt_pkrtz(a, b);
  return __builtin_bit_cast(f16x2, r);
}

// tanh via hw exp2+rcp: exact at +-inf, ~1e-6 abs err, ~5 VALU ops
static __device__ inline float fast_tanh(float x) {
  float e = __builtin_amdgcn_exp2f(x * 2.885390081777927f);  // exp(2x)
  return 1.f - 2.f * __builtin_amdgcn_rcpf(1.f + e);
}

// async global->LDS, 16B/lane; LDS dest wave-uniform (HW adds lane*16).
static __device__ inline void gld16(const _Float16* g, _Float16* l) {
  __builtin_amdgcn_global_load_lds(
      (const __attribute__((address_space(1))) void*)g,
      (__attribute__((address_space(3))) void*)l, 16, 0, 0);
}

// ---------------------------------------------------------------------------
// zero all of d_out (qpb lives in context region, score in weights region;
// both are atomic targets). 96 blocks x 1024 = 98304 floats.
// ---------------------------------------------------------------------------
__global__ void zero_kernel(float* __restrict__ p) {
  p[blockIdx.x * 1024 + threadIdx.x] = 0.f;
}

// ---------------------------------------------------------------------------
// Kernel A: qpb[b][u] += partial of query@W2 (+b1+b2 once).
// Grid 64 = (u0 in 8 x 128u) x (dsl in 8 x 256d). W2 read exactly once (8 MB,
// was 256 MB in R5's layout). Query slice in LDS (broadcast reads).
// ---------------------------------------------------------------------------
__global__ __launch_bounds__(256) void qproj_kernel(
    const float* __restrict__ query, const float* __restrict__ W2,
    const float* __restrict__ b1, const float* __restrict__ b2,
    float* __restrict__ qpb) {
  __shared__ float qs[32][256];  // 32 KB
  const int u0 = (blockIdx.x & 7) * 128;
  const int dsl = blockIdx.x >> 3;
  const int d0 = dsl * 256;
  const int tid = threadIdx.x;
  const int ul = tid & 127, half = tid >> 7;

  for (int i = tid; i < 32 * 64; i += 256) {  // 2048 float4 = 32 KB
    int b = i >> 6, dq = i & 63;
    *(float4*)&qs[b][dq * 4] = *(const float4*)(query + b * DD + d0 + dq * 4);
  }
  __syncthreads();

  float acc[32];
#pragma unroll
  for (int b = 0; b < 32; ++b) acc[b] = 0.f;

  const float* wcol = W2 + (size_t)(d0 + half * 128) * UU + u0 + ul;
  for (int dd = 0; dd < 128; dd += 4) {
    float w0 = wcol[(size_t)(dd + 0) * UU];
    float w1 = wcol[(size_t)(dd + 1) * UU];
    float w2 = wcol[(size_t)(dd + 2) * UU];
    float w3 = wcol[(size_t)(dd + 3) * UU];
#pragma unroll
    for (int b = 0; b < 32; ++b) {
      float4 q4 = *(const float4*)&qs[b][half * 128 + dd];
      acc[b] += q4.x * w0 + q4.y * w1 + q4.z * w2 + q4.w * w3;
    }
  }

  const int u = u0 + ul;
  const float bias = (dsl == 0 && half == 0) ? (b1[u] + b2[u]) : 0.f;
#pragma unroll
  for (int b = 0; b < 32; ++b) atomicAdd(&qpb[b * UU + u], acc[b] + bias);
}

// ---------------------------------------------------------------------------
// Pre-pass 1: values fp32 -> packed fp16 MFMA image (proven in R5).
// ---------------------------------------------------------------------------
__global__ __launch_bounds__(256) void pack_values_kernel(
    const float* __restrict__ v, _Float16* __restrict__ vhp) {
  __shared__ _Float16 img[8192];  // 16 KB
  const int mTile = blockIdx.x >> 5;
  const int kc = blockIdx.x & 31;
  const int tid = threadIdx.x;

#pragma unroll
  for (int i = 0; i < 4; ++i) {
    int idx = i * 256 + tid;
    int row = idx >> 3, khi = idx & 7;
    const float* src = v + ((size_t)(mTile * 128 + row)) * DD + kc * 64 + khi * 8;
    float4 x = *(const float4*)src;
    float4 y = *(const float4*)(src + 4);
    H8 h;
    h.p[0] = pk(x.x, x.y); h.p[1] = pk(x.z, x.w);
    h.p[2] = pk(y.x, y.y); h.p[3] = pk(y.z, y.w);
    *(f16x8*)&img[(khi * 128 + (row ^ khi)) * 8] = h.v;
  }
  __syncthreads();

  _Float16* out = vhp + ((size_t)mTile * 32 + kc) * 8192;
#pragma unroll
  for (int i = 0; i < 4; ++i) {
    int p = i * 256 + tid;
    int khi = p >> 7, row = p & 127;
    *(f16x8*)(out + (size_t)p * 8) = *(const f16x8*)&img[(khi * 128 + (row ^ khi)) * 8];
  }
}

// ---------------------------------------------------------------------------
// Pre-pass 2: W1 -> packed fp16 image of W1^T (proven in R5).
// ---------------------------------------------------------------------------
__global__ __launch_bounds__(256) void pack_w1_kernel(
    const float* __restrict__ W1, _Float16* __restrict__ w1p) {
  __shared__ _Float16 img[8192];
  const int nTile = blockIdx.x >> 5;
  const int kc = blockIdx.x & 31;
  const int tid = threadIdx.x;

#pragma unroll
  for (int i = 0; i < 32; ++i) {
    int idx = i * 256 + tid;
    int ul = idx & 127, kl = idx >> 7;
    float x = W1[(size_t)(kc * 64 + kl) * UU + nTile * 128 + ul];
    int khi = kl >> 3, klo = kl & 7;
    img[(khi * 128 + (ul ^ khi)) * 8 + klo] = (_Float16)x;
  }
  __syncthreads();

  _Float16* out = w1p + ((size_t)nTile * 32 + kc) * 8192;
#pragma unroll
  for (int i = 0; i < 4; ++i) {
    int p = i * 256 + tid;
    int khi = p >> 7, row = p & 127;
    *(f16x8*)(out + (size_t)p * 8) = *(const f16x8*)&img[(khi * 128 + (row ^ khi)) * 8];
  }
}

// ---------------------------------------------------------------------------
// Kernel B: fused score GEMM from packed images. Tile 128x128, BK=64,
// XCD swizzle, flat 16-KB chunk staging via global_load_lds. (R5 core,
// epilogue now uses fast_tanh.)
// ---------------------------------------------------------------------------
__global__ __launch_bounds__(256) void score_gemm_p_kernel(
    const _Float16* __restrict__ vhp, const _Float16* __restrict__ w1p,
    const float* __restrict__ qpb, const float* __restrict__ V,
    float* __restrict__ score) {
  __shared__ _Float16 aS[8192];  // 16 KB
  __shared__ _Float16 bS[8192];  // 16 KB

  const int tid = threadIdx.x;
  const int r = blockIdx.x & 7, q = blockIdx.x >> 3;
  const int mTile = r * 32 + (q >> 3);
  const int nTile = q & 7;
  const int mBase = mTile * 128, nBase = nTile * 128;

  const int lane = tid & 63, wave = tid >> 6;
  const int wm = (wave & 1) * 64, wn = (wave >> 1) * 64;
  const int quad = lane >> 4, c16 = lane & 15;

  const _Float16* gA = vhp + (size_t)mTile * 32 * 8192 + lane * 8;
  const _Float16* gB = w1p + (size_t)nTile * 32 * 8192 + lane * 8;

  f32x4 acc[4][4];
#pragma unroll
  for (int mi = 0; mi < 4; ++mi)
#pragma unroll
    for (int ni = 0; ni < 4; ++ni) acc[mi][ni] = (f32x4)0.f;

  for (int kc = 0; kc < 32; ++kc) {
    __syncthreads();
#pragma unroll
    for (int j = 0; j < 4; ++j) {
      int s = wave * 4 + j;
      gld16(gA + (size_t)kc * 8192 + s * 512, &aS[s * 512]);
      gld16(gB + (size_t)kc * 8192 + s * 512, &bS[s * 512]);
    }
    __syncthreads();

#pragma unroll
    for (int h = 0; h < 2; ++h) {
      f16x8 af[4], bf[4];
#pragma unroll
      for (int i = 0; i < 4; ++i) {
        af[i] = *(const f16x8*)&aS[((h * 4 + quad) * 128 + wm + i * 16 + c16) * 8];
        bf[i] = *(const f16x8*)&bS[((h * 4 + quad) * 128 + wn + i * 16 + c16) * 8];
      }
#pragma unroll
      for (int mi = 0; mi < 4; ++mi)
#pragma unroll
        for (int ni = 0; ni < 4; ++ni)
          acc[mi][ni] = __builtin_amdgcn_mfma_f32_16x16x32_f16(
              af[mi], bf[ni], acc[mi][ni], 0, 0, 0);
    }
  }

  const int b = mBase >> 10;
  float qv[4], vv[4];
#pragma unroll
  for (int ni = 0; ni < 4; ++ni) {
    int ug = nBase + wn + ni * 16 + c16;
    qv[ni] = qpb[b * UU + ug];
    vv[ni] = V[ug];
  }
#pragma unroll
  for (int mi = 0; mi < 4; ++mi) {
#pragma unroll
    for (int reg = 0; reg < 4; ++reg) {
      float p = fast_tanh(acc[mi][0][reg] + qv[0]) * vv[0] +
                fast_tanh(acc[mi][1][reg] + qv[1]) * vv[1] +
                fast_tanh(acc[mi][2][reg] + qv[2]) * vv[2] +
                fast_tanh(acc[mi][3][reg] + qv[3]) * vv[3];
      p += __shfl_xor(p, 1, 64);
      p += __shfl_xor(p, 2, 64);
      p += __shfl_xor(p, 4, 64);
      p += __shfl_xor(p, 8, 64);
      if (c16 == 0) {
        int mrow = mBase + wm + mi * 16 + quad * 4 + reg;
        atomicAdd(&score[mrow], p);
      }
    }
  }
}

// ---------------------------------------------------------------------------
// Kernel B fallback (small ws): fp32-in, cvt per tile (R3 core, fast_tanh).
// ---------------------------------------------------------------------------
__global__ __launch_bounds__(256) void score_gemm_kernel(
    const float* __restrict__ values, const float* __restrict__ W1,
    const float* __restrict__ qpb, const float* __restrict__ V,
    float* __restrict__ score) {
  __shared__ _Float16 aS[4 * 128 * 8];
  __shared__ _Float16 bS[4 * 128 * 8];

  const int tid = threadIdx.x;
  const int mBase = (blockIdx.x >> 3) * 128;
  const int nBase = (blockIdx.x & 7) * 128;

  const int am = tid >> 1;
  const int akh = (tid & 1) * 16;
  const float* aG = values + (size_t)(mBase + am) * DD + akh;
  const int aOff0 = (((tid & 1) * 2) * 128 + am) * 8;
  const int bu2 = (tid & 63) * 2;
  const int bkq = tid >> 6;
  const float* bG = W1 + (size_t)(bkq * 8) * UU + nBase + bu2;
  const int bOff0 = (bkq * 128 + bu2) * 8;

  const int lane = tid & 63;
  const int wave = tid >> 6;
  const int wm = (wave & 1) * 64;
  const int wn = (wave >> 1) * 64;
  const int quad = lane >> 4;
  const int c16 = lane & 15;

  f32x4 acc[4][4];
#pragma unroll
  for (int mi = 0; mi < 4; ++mi)
#pragma unroll
    for (int ni = 0; ni < 4; ++ni) acc[mi][ni] = (f32x4)0.f;

  for (int k0 = 0; k0 < DD; k0 += 32) {
    float4 a0 = *(const float4*)(aG + k0 + 0);
    float4 a1 = *(const float4*)(aG + k0 + 4);
    float4 a2 = *(const float4*)(aG + k0 + 8);
    float4 a3 = *(const float4*)(aG + k0 + 12);
    const float* bRow = bG + (size_t)k0 * UU;
    float2 g0 = *(const float2*)(bRow + 0 * UU);
    float2 g1 = *(const float2*)(bRow + 1 * UU);
    float2 g2 = *(const float2*)(bRow + 2 * UU);
    float2 g3 = *(const float2*)(bRow + 3 * UU);
    float2 g4 = *(const float2*)(bRow + 4 * UU);
    float2 g5 = *(const float2*)(bRow + 5 * UU);
    float2 g6 = *(const float2*)(bRow + 6 * UU);
    float2 g7 = *(const float2*)(bRow + 7 * UU);

    __syncthreads();

    H8 ha0, ha1, hb0, hb1;
    ha0.p[0] = pk(a0.x, a0.y); ha0.p[1] = pk(a0.z, a0.w);
    ha0.p[2] = pk(a1.x, a1.y); ha0.p[3] = pk(a1.z, a1.w);
    ha1.p[0] = pk(a2.x, a2.y); ha1.p[1] = pk(a2.z, a2.w);
    ha1.p[2] = pk(a3.x, a3.y); ha1.p[3] = pk(a3.z, a3.w);
    *(f16x8*)&aS[aOff0] = ha0.v;
    *(f16x8*)&aS[aOff0 + 1024] = ha1.v;

    hb0.p[0] = pk(g0.x, g1.x); hb0.p[1] = pk(g2.x, g3.x);
    hb0.p[2] = pk(g4.x, g5.x); hb0.p[3] = pk(g6.x, g7.x);
    hb1.p[0] = pk(g0.y, g1.y); hb1.p[1] = pk(g2.y, g3.y);
    hb1.p[2] = pk(g4.y, g5.y); hb1.p[3] = pk(g6.y, g7.y);
    *(f16x8*)&bS[bOff0] = hb0.v;
    *(f16x8*)&bS[bOff0 + 8] = hb1.v;

    __syncthreads();

    f16x8 af[4], bf[4];
#pragma unroll
    for (int i = 0; i < 4; ++i) {
      af[i] = *(const f16x8*)&aS[(quad * 128 + wm + i * 16 + c16) * 8];
      bf[i] = *(const f16x8*)&bS[(quad * 128 + wn + i * 16 + c16) * 8];
    }
#pragma unroll
    for (int mi = 0; mi < 4; ++mi)
#pragma unroll
      for (int ni = 0; ni < 4; ++ni)
        acc[mi][ni] = __builtin_amdgcn_mfma_f32_16x16x32_f16(
            af[mi], bf[ni], acc[mi][ni], 0, 0, 0);
  }

  const int b = mBase >> 10;
  float qv[4], vv[4];
#pragma unroll
  for (int ni = 0; ni < 4; ++ni) {
    int ug = nBase + wn + ni * 16 + c16;
    qv[ni] = qpb[b * UU + ug];
    vv[ni] = V[ug];
  }
#pragma unroll
  for (int mi = 0; mi < 4; ++mi) {
#pragma unroll
    for (int reg = 0; reg < 4; ++reg) {
      float p = fast_tanh(acc[mi][0][reg] + qv[0]) * vv[0] +
                fast_tanh(acc[mi][1][reg] + qv[1]) * vv[1] +
                fast_tanh(acc[mi][2][reg] + qv[2]) * vv[2] +
                fast_tanh(acc[mi][3][reg] + qv[3]) * vv[3];
      p += __shfl_xor(p, 1, 64);
      p += __shfl_xor(p, 2, 64);
      p += __shfl_xor(p, 4, 64);
      p += __shfl_xor(p, 8, 64);
      if (c16 == 0) {
        int mrow = mBase + wm + mi * 16 + quad * 4 + reg;
        atomicAdd(&score[mrow], p);
      }
    }
  }
}

// ---------------------------------------------------------------------------
// Kernel C: softmax over T per batch, in-place
// ---------------------------------------------------------------------------
__global__ __launch_bounds__(256) void softmax_kernel(float* __restrict__ sw) {
  __shared__ float red[256];
  const int b = blockIdx.x;
  const int tid = threadIdx.x;
  float* s = sw + b * TS;

  float vals[4];
  float m = -1e30f;
#pragma unroll
  for (int i = 0; i < 4; ++i) {
    vals[i] = s[tid + 256 * i];
    m = fmaxf(m, vals[i]);
  }
  red[tid] = m;
  __syncthreads();
  for (int off = 128; off > 0; off >>= 1) {
    if (tid < off) red[tid] = fmaxf(red[tid], red[tid + off]);
    __syncthreads();
  }
  m = red[0];
  __syncthreads();

  float sum = 0.f;
#pragma unroll
  for (int i = 0; i < 4; ++i) {
    vals[i] = expf(vals[i] - m);
    sum += vals[i];
  }
  red[tid] = sum;
  __syncthreads();
  for (int off = 128; off > 0; off >>= 1) {
    if (tid < off) red[tid] += red[tid + off];
    __syncthreads();
  }
  const float inv = 1.f / red[0];
#pragma unroll
  for (int i = 0; i < 4; ++i) s[tid + 256 * i] = vals[i] * inv;
}

// ---------------------------------------------------------------------------
// Kernel D: context[b][d] = sum_t weights[b][t] * values[b][t][d]
// 256 blocks = b(32) x dchunk(8, 256-wide). 1024 thr = slice(16) x dl(64),
// float4 loads (1 KB/wave-inst), LDS partial reduce over slices.
// ---------------------------------------------------------------------------
__global__ __launch_bounds__(1024) void context_kernel(
    const float* __restrict__ values, const float* __restrict__ weights,
    float* __restrict__ context) {
  __shared__ float wl[TS];
  __shared__ float4 part[15][64];
  const int b = blockIdx.x >> 3;
  const int d0 = (blockIdx.x & 7) * 256;
  const int tid = threadIdx.x;
  const int slice = tid >> 6, dl = tid & 63;

  wl[tid] = weights[b * TS + tid];
  __syncthreads();

  const float* vb = values + ((size_t)b * TS + slice * 64) * DD + d0 + dl * 4;
  float4 acc = {0.f, 0.f, 0.f, 0.f};
#pragma unroll 8
  for (int t = 0; t < 64; ++t) {
    float w = wl[slice * 64 + t];
    float4 v4 = *(const float4*)(vb + (size_t)t * DD);
    acc.x += w * v4.x; acc.y += w * v4.y;
    acc.z += w * v4.z; acc.w += w * v4.w;
  }

  if (slice) part[slice - 1][dl] = acc;
  __syncthreads();
  if (slice == 0) {
#pragma unroll
    for (int i = 0; i < 15; ++i) {
      float4 p = part[i][dl];
      acc.x += p.x; acc.y += p.y; acc.z += p.z; acc.w += p.w;
    }
    *(float4*)(context + b * DD + d0 + dl * 4) = acc;
  }
}

// ---------------------------------------------------------------------------
extern "C" void kernel_launch(void* const* d_in, const int* in_sizes, int n_in,
                              void* d_out, int out_size, void* d_ws, size_t ws_size,
                              hipStream_t stream) {
  const float* query  = (const float*)d_in[0];
  const float* values = (const float*)d_in[1];
  const float* W1     = (const float*)d_in[2];
  const float* b1     = (const float*)d_in[3];
  const float* W2     = (const float*)d_in[4];
  const float* b2     = (const float*)d_in[5];
  const float* V      = (const float*)d_in[6];
  // d_in[7] = bv cancels in softmax; unused.

  float* out = (float*)d_out;
  float* context = out;            // B*D (output 0)
  float* weights = out + BB * DD;  // B*T (output 1)

  float* qpb   = context;  // atomic target; overwritten by context kernel later
  float* score = weights;  // atomic target; softmax in-place

  const size_t need = (size_t)BB * TS * DD * 2 + (size_t)DD * UU * 2;
  const bool big_ws = ws_size >= need;

  zero_kernel<<<96, 1024, 0, stream>>>(out);  // zeros qpb + score regions
  qproj_kernel<<<64, 256, 0, stream>>>(query, W2, b1, b2, qpb);

  if (big_ws) {
    _Float16* vhp = (_Float16*)d_ws;
    _Float16* w1p = vhp + (size_t)BB * TS * DD;
    pack_values_kernel<<<256 * 32, 256, 0, stream>>>(values, vhp);
    pack_w1_kernel<<<8 * 32, 256, 0, stream>>>(W1, w1p);
    score_gemm_p_kernel<<<(BB * TS / 128) * (UU / 128), 256, 0, stream>>>(
        vhp, w1p, qpb, V, score);
  } else {
    score_gemm_kernel<<<(BB * TS / 128) * (UU / 128), 256, 0, stream>>>(
        values, W1, qpb, V, score);
  }

  softmax_kernel<<<BB, 256, 0, stream>>>(score);
  context_kernel<<<BB * 8, 1024, 0, stream>>>(values, weights, context);
}